// Round 6
// baseline (1039.159 us; speedup 1.0000x reference)
//
#include <hip/hip_runtime.h>

// RGCN encoder: N=20000 nodes, E=640000 edges, F=64, H=128, L=2 layers,
// D=3 edge-attr dims, R=8 relations, block-diag B=4 blocks of c=32.
//
// R6: relation-sorted edge lists. For each j in 0..2, elist_j orders each
// dst's edges by relation (sub-segment bounds derived from cnt8 prefix), so
// the agg inner loop is a plain contiguous sum: 1 gather + 1 add per edge
// per j, no predication (R5 paid 24x cmp/cndmask/add per edge). Gather
// traffic triples but stays L2-resident. Everything else as R5.

constexpr int H  = 128;
constexpr int F  = 64;
constexpr int D  = 3;
constexpr int R  = 8;
constexpr int B  = 4;
constexpr int C  = 32;
constexpr int ROWS = 8;     // gemm_h0
constexpr int ROWSB = 16;   // matB
constexpr int SCAN_CHUNK = 512;

// ---------------- CSR build (per-dst, relation-sorted per j) ----------------

__global__ void count_edges(const int* __restrict__ ei, const int* __restrict__ attr,
                            int* __restrict__ cnt8, int E) {
  int e = blockIdx.x * 256 + threadIdx.x;
  if (e >= E) return;
  int dst = ei[E + e];
  #pragma unroll
  for (int j = 0; j < D; ++j) {
    int r = attr[e * D + j];
    atomicAdd(&cnt8[dst * (D * R) + j * R + r], 1);
  }
}

__global__ void indeg_from_cnt8(const int* __restrict__ cnt8, int* __restrict__ indeg, int N) {
  int n = blockIdx.x * 256 + threadIdx.x;
  if (n >= N) return;
  int s = 0;
  #pragma unroll
  for (int r = 0; r < R; ++r) s += cnt8[n * (D * R) + r];  // j=0 row counts each edge once
  indeg[n] = s;
}

__global__ void scan_a(const int* __restrict__ cnt, int* __restrict__ cexcl,
                       int* __restrict__ bsum, int nseg) {
  __shared__ int tmp[2][SCAN_CHUNK];
  int t = threadIdx.x;
  int gid = blockIdx.x * SCAN_CHUNK + t;
  int v = (gid < nseg) ? cnt[gid] : 0;
  int pa = 0;
  tmp[0][t] = v;
  __syncthreads();
  for (int off = 1; off < SCAN_CHUNK; off <<= 1) {
    tmp[1 - pa][t] = tmp[pa][t] + ((t >= off) ? tmp[pa][t - off] : 0);
    pa = 1 - pa;
    __syncthreads();
  }
  int incl = tmp[pa][t];
  if (gid < nseg) cexcl[gid] = incl - v;
  if (t == SCAN_CHUNK - 1) bsum[blockIdx.x] = incl;
}

__global__ void scan_b(int* __restrict__ bsum, int nblk) {
  __shared__ int tmp[2][1024];
  int t = threadIdx.x;
  int v = (t < nblk) ? bsum[t] : 0;
  int pa = 0;
  tmp[0][t] = v;
  __syncthreads();
  for (int off = 1; off < 1024; off <<= 1) {
    tmp[1 - pa][t] = tmp[pa][t] + ((t >= off) ? tmp[pa][t - off] : 0);
    pa = 1 - pa;
    __syncthreads();
  }
  if (t < nblk) bsum[t] = tmp[pa][t] - v;  // exclusive
}

__global__ void scan_c(const int* __restrict__ cexcl, const int* __restrict__ bsum,
                       int* __restrict__ offs, int nseg, int total) {
  int gid = blockIdx.x * 256 + threadIdx.x;
  if (gid < nseg) offs[gid] = cexcl[gid] + bsum[gid / SCAN_CHUNK];
  if (gid == 0) offs[nseg] = total;
}

// cursor8[n][j][r] = offs[n] + sum_{r'<r} cnt8[n][j][r']
__global__ void build_cursor8(const int* __restrict__ cnt8, const int* __restrict__ offs,
                              int* __restrict__ cursor8, int N) {
  int n = blockIdx.x * 256 + threadIdx.x;
  if (n >= N) return;
  const int base = offs[n];
  #pragma unroll
  for (int j = 0; j < D; ++j) {
    int o = base;
    #pragma unroll
    for (int r = 0; r < R; ++r) {
      cursor8[n * (D * R) + j * R + r] = o;
      o += cnt8[n * (D * R) + j * R + r];
    }
  }
}

__global__ void fill_edges3(const int* __restrict__ ei, const int* __restrict__ attr,
                            int* __restrict__ cursor8,
                            int* __restrict__ el0, int* __restrict__ el1,
                            int* __restrict__ el2, int E) {
  int e = blockIdx.x * 256 + threadIdx.x;
  if (e >= E) return;
  int src = ei[e];
  int dst = ei[E + e];
  int r0 = attr[e * D + 0], r1 = attr[e * D + 1], r2 = attr[e * D + 2];
  int p0 = atomicAdd(&cursor8[dst * (D * R) + r0], 1);
  int p1 = atomicAdd(&cursor8[dst * (D * R) + R + r1], 1);
  int p2 = atomicAdd(&cursor8[dst * (D * R) + 2 * R + r2], 1);
  el0[p0] = src;
  el1[p1] = src;
  el2[p2] = src;
}

// ---------------- h0 = x @ emb ----------------

__global__ __launch_bounds__(128) void gemm_h0(const float* __restrict__ x,
                                               const float* __restrict__ emb,
                                               float* __restrict__ h0, int N) {
  __shared__ float xs[ROWS][F];
  int r0 = blockIdx.x * ROWS;
  for (int i = threadIdx.x; i < ROWS * F; i += 128)
    xs[i >> 6][i & 63] = x[(size_t)r0 * F + i];
  __syncthreads();
  int d = threadIdx.x;
  float acc[ROWS] = {};
  for (int k = 0; k < F; ++k) {
    float ev = emb[k * H + d];
    #pragma unroll
    for (int r = 0; r < ROWS; ++r) acc[r] = fmaf(xs[r][k], ev, acc[r]);
  }
  #pragma unroll
  for (int r = 0; r < ROWS; ++r) h0[(size_t)(r0 + r) * H + d] = acc[r];
}

// ---------------- aggregation + block-diag transform ----------------
// Block = 128 threads per dst node; thread d owns channel d. Edges arrive
// relation-sorted per j, so each (j,rel) sub-segment is a contiguous plain
// sum: no predication, no LDS in the edge loop.

__global__ __launch_bounds__(128) void agg_kernel(
    const float* __restrict__ hsrc, const int* __restrict__ offs,
    const int* __restrict__ el0, const int* __restrict__ el1,
    const int* __restrict__ el2, const int* __restrict__ cnt8,
    const float* __restrict__ Wall, float* __restrict__ m, int N) {
  const int n = blockIdx.x;
  const int d = threadIdx.x;
  __shared__ float s[D * R][H];   // 12 KB
  __shared__ float sinv[D * R];
  __shared__ int cnts[D * R];

  if (d < D * R) {
    int c = cnt8[n * (D * R) + d];
    cnts[d] = c;
    sinv[d] = (c > 0) ? 1.f / (float)c : 0.f;
  }
  __syncthreads();

  const int beg = offs[n];
  const float* __restrict__ hd = hsrc + d;
  const int* const els[D] = {el0, el1, el2};

  #pragma unroll
  for (int j = 0; j < D; ++j) {
    const int* __restrict__ el = els[j];
    int off = beg;
    for (int r = 0; r < R; ++r) {
      const int cnt = cnts[j * R + r];
      const int* __restrict__ ep = el + off;
      float a0 = 0.f, a1 = 0.f, a2 = 0.f, a3 = 0.f;
      int e = 0;
      for (; e + 4 <= cnt; e += 4) {
        const int s0 = ep[e], s1 = ep[e + 1], s2 = ep[e + 2], s3 = ep[e + 3];
        a0 += hd[(size_t)s0 * H];
        a1 += hd[(size_t)s1 * H];
        a2 += hd[(size_t)s2 * H];
        a3 += hd[(size_t)s3 * H];
      }
      for (; e < cnt; ++e) a0 += hd[(size_t)ep[e] * H];
      s[j * R + r][d] = (a0 + a1) + (a2 + a3);
      off += cnt;
    }
  }
  __syncthreads();

  const int b = d >> 5, dd = d & 31;
  #pragma unroll
  for (int j = 0; j < D; ++j) {
    float a = 0.f;
    for (int r = 0; r < R; ++r) {
      const int jr = j * R + r;
      const float* __restrict__ Wr = Wall + (((size_t)jr * B + b) * C) * C + dd;
      const float4* __restrict__ srow4 = (const float4*)&s[jr][b * C];
      float t = 0.f;
      #pragma unroll
      for (int c4 = 0; c4 < C / 4; ++c4) {
        const float4 sv = srow4[c4];
        t = fmaf(sv.x, Wr[(size_t)(4 * c4 + 0) * C], t);
        t = fmaf(sv.y, Wr[(size_t)(4 * c4 + 1) * C], t);
        t = fmaf(sv.z, Wr[(size_t)(4 * c4 + 2) * C], t);
        t = fmaf(sv.w, Wr[(size_t)(4 * c4 + 3) * C], t);
      }
      a = fmaf(t, sinv[jr], a);
    }
    m[((size_t)j * N + n) * H + d] = a;
  }
}

// ---------------- dense root matmul + msg add + relu ----------------

__global__ __launch_bounds__(128) void matB(
    const float* __restrict__ h, const float* __restrict__ m,
    const float* __restrict__ rootall, const float* __restrict__ biasall,
    float* __restrict__ out, int N_all, int N) {
  const int j = blockIdx.y;
  const int row0 = blockIdx.x * ROWSB;
  const int d = threadIdx.x;
  const float* root = rootall + (size_t)j * H * H;
  __shared__ float hs[ROWSB][H];

  #pragma unroll
  for (int r = 0; r < ROWSB; ++r)
    hs[r][d] = h[(size_t)(row0 + r) * H + d];
  __syncthreads();

  const float bias = biasall[j * H + d];
  float acc[ROWSB];
  #pragma unroll
  for (int r = 0; r < ROWSB; ++r) acc[r] = bias;

  for (int k = 0; k < H; ++k) {
    float rk = root[(size_t)k * H + d];
    #pragma unroll
    for (int r = 0; r < ROWSB; ++r) acc[r] = fmaf(hs[r][k], rk, acc[r]);
  }

  if (row0 + ROWSB <= N) {
    #pragma unroll
    for (int r = 0; r < ROWSB; ++r)
      acc[r] += m[((size_t)j * N + row0 + r) * H + d];
  }

  #pragma unroll
  for (int r = 0; r < ROWSB; ++r)
    out[((size_t)j * N_all + row0 + r) * H + d] = fmaxf(acc[r], 0.f);
}

// ---------------- launch ----------------

extern "C" void kernel_launch(void* const* d_in, const int* in_sizes, int n_in,
                              void* d_out, int out_size, void* d_ws, size_t ws_size,
                              hipStream_t stream) {
  const float* x    = (const float*)d_in[0];
  const int*   ei   = (const int*)d_in[1];
  const int*   attr = (const int*)d_in[2];
  const float* emb  = (const float*)d_in[3];
  const float* cw   = (const float*)d_in[4];
  const float* cr   = (const float*)d_in[5];
  const float* cb   = (const float*)d_in[6];
  float* out = (float*)d_out;

  const int N = in_sizes[0] / F;   // 20000
  const int E = in_sizes[1] / 2;   // 640000

  char* ws = (char*)d_ws;
  size_t woff = 0;
  auto alloc = [&](size_t bytes) -> void* {
    void* p = ws + woff;
    woff = (woff + bytes + 255) & ~(size_t)255;
    return p;
  };
  float* h0      = (float*)alloc((size_t)N * H * 4);
  float* h1      = (float*)alloc((size_t)D * N * H * 4);
  float* m       = (float*)alloc((size_t)D * N * H * 4);
  int*   indeg   = (int*)alloc((size_t)N * 4);
  int*   cnt8    = (int*)alloc((size_t)N * D * R * 4);
  int*   cexcl   = (int*)alloc((size_t)N * 4);
  int*   bsum    = (int*)alloc(4096);
  int*   offs    = (int*)alloc((size_t)(N + 1) * 4);
  int*   cursor8 = (int*)alloc((size_t)N * D * R * 4);
  int*   el0     = (int*)alloc((size_t)E * 4);
  int*   el1     = (int*)alloc((size_t)E * 4);
  int*   el2     = (int*)alloc((size_t)E * 4);

  hipMemsetAsync(cnt8, 0, (size_t)N * D * R * 4, stream);
  count_edges<<<(E + 255) / 256, 256, 0, stream>>>(ei, attr, cnt8, E);
  indeg_from_cnt8<<<(N + 255) / 256, 256, 0, stream>>>(cnt8, indeg, N);

  int nch = (N + SCAN_CHUNK - 1) / SCAN_CHUNK;  // 40
  scan_a<<<nch, SCAN_CHUNK, 0, stream>>>(indeg, cexcl, bsum, N);
  scan_b<<<1, 1024, 0, stream>>>(bsum, nch);
  scan_c<<<(N + 255) / 256, 256, 0, stream>>>(cexcl, bsum, offs, N, E);
  build_cursor8<<<(N + 255) / 256, 256, 0, stream>>>(cnt8, offs, cursor8, N);
  fill_edges3<<<(E + 255) / 256, 256, 0, stream>>>(ei, attr, cursor8, el0, el1, el2, E);

  gemm_h0<<<N / ROWS, 128, 0, stream>>>(x, emb, h0, N);

  // layer 0
  agg_kernel<<<N, 128, 0, stream>>>(h0, offs, el0, el1, el2, cnt8, cw, m, N);
  {
    dim3 grid(N / ROWSB, D);
    matB<<<grid, 128, 0, stream>>>(h0, m, cr, cb, h1, N, N);
  }
  // layer 1 (gathers only rows < N of h1)
  agg_kernel<<<N, 128, 0, stream>>>(h1, offs, el0, el1, el2, cnt8,
                                    cw + (size_t)D * R * B * C * C, m, N);
  {
    dim3 grid((D * N) / ROWSB, D);
    matB<<<grid, 128, 0, stream>>>(h1, m,
                                   cr + (size_t)D * H * H,
                                   cb + (size_t)D * H,
                                   out, D * N, N);
  }
}

// Round 7
// 818.419 us; speedup vs baseline: 1.2697x; 1.2697x over previous
//
#include <hip/hip_runtime.h>

// RGCN encoder: N=20000 nodes, E=640000 edges, F=64, H=128, L=2 layers,
// D=3 edge-attr dims, R=8 relations, block-diag B=4 blocks of c=32.
//
// R7: single gather per edge (R5 traffic) + wave-uniform SCALAR relation
// selection: the whole 128-thread block processes one edge at a time, so the
// packed relation triple is wave-uniform -> readfirstlane to SGPR -> uniform
// switch (s_cmp/s_cbranch, scalar pipe) with a single v_add_f32 body into a
// compile-time-indexed VGPR accumulator. No LDS ops, no predication fan-out
// in the edge loop.

constexpr int H  = 128;
constexpr int F  = 64;
constexpr int D  = 3;
constexpr int R  = 8;
constexpr int B  = 4;
constexpr int C  = 32;
constexpr int ROWS = 8;     // gemm_h0
constexpr int ROWSB = 16;   // matB
constexpr int SCAN_CHUNK = 512;

// ---------------- CSR build (per-dst) ----------------

__global__ void count_edges(const int* __restrict__ ei, const int* __restrict__ attr,
                            int* __restrict__ cnt8, int E) {
  int e = blockIdx.x * 256 + threadIdx.x;
  if (e >= E) return;
  int dst = ei[E + e];
  #pragma unroll
  for (int j = 0; j < D; ++j) {
    int r = attr[e * D + j];
    atomicAdd(&cnt8[dst * (D * R) + j * R + r], 1);
  }
}

__global__ void indeg_from_cnt8(const int* __restrict__ cnt8, int* __restrict__ indeg, int N) {
  int n = blockIdx.x * 256 + threadIdx.x;
  if (n >= N) return;
  int s = 0;
  #pragma unroll
  for (int r = 0; r < R; ++r) s += cnt8[n * (D * R) + r];  // j=0 row counts each edge once
  indeg[n] = s;
}

__global__ void scan_a(const int* __restrict__ cnt, int* __restrict__ cexcl,
                       int* __restrict__ bsum, int nseg) {
  __shared__ int tmp[2][SCAN_CHUNK];
  int t = threadIdx.x;
  int gid = blockIdx.x * SCAN_CHUNK + t;
  int v = (gid < nseg) ? cnt[gid] : 0;
  int pa = 0;
  tmp[0][t] = v;
  __syncthreads();
  for (int off = 1; off < SCAN_CHUNK; off <<= 1) {
    tmp[1 - pa][t] = tmp[pa][t] + ((t >= off) ? tmp[pa][t - off] : 0);
    pa = 1 - pa;
    __syncthreads();
  }
  int incl = tmp[pa][t];
  if (gid < nseg) cexcl[gid] = incl - v;
  if (t == SCAN_CHUNK - 1) bsum[blockIdx.x] = incl;
}

__global__ void scan_b(int* __restrict__ bsum, int nblk) {
  __shared__ int tmp[2][1024];
  int t = threadIdx.x;
  int v = (t < nblk) ? bsum[t] : 0;
  int pa = 0;
  tmp[0][t] = v;
  __syncthreads();
  for (int off = 1; off < 1024; off <<= 1) {
    tmp[1 - pa][t] = tmp[pa][t] + ((t >= off) ? tmp[pa][t - off] : 0);
    pa = 1 - pa;
    __syncthreads();
  }
  if (t < nblk) bsum[t] = tmp[pa][t] - v;  // exclusive
}

__global__ void scan_c(const int* __restrict__ cexcl, const int* __restrict__ bsum,
                       int* __restrict__ offs, int nseg, int total) {
  int gid = blockIdx.x * 256 + threadIdx.x;
  if (gid < nseg) offs[gid] = cexcl[gid] + bsum[gid / SCAN_CHUNK];
  if (gid == 0) offs[nseg] = total;
}

__global__ void copy_int(const int* __restrict__ a, int* __restrict__ b, int n) {
  int i = blockIdx.x * 256 + threadIdx.x;
  if (i < n) b[i] = a[i];
}

__global__ void fill_edges(const int* __restrict__ ei, const int* __restrict__ attr,
                           int* __restrict__ cursor, unsigned* __restrict__ elist, int E) {
  int e = blockIdx.x * 256 + threadIdx.x;
  if (e >= E) return;
  int src = ei[e];
  int dst = ei[E + e];
  unsigned r0 = attr[e * D + 0], r1 = attr[e * D + 1], r2 = attr[e * D + 2];
  unsigned u = (unsigned)src | (r0 << 16) | (r1 << 20) | (r2 << 24);
  int p = atomicAdd(&cursor[dst], 1);
  elist[p] = u;
}

// ---------------- h0 = x @ emb ----------------

__global__ __launch_bounds__(128) void gemm_h0(const float* __restrict__ x,
                                               const float* __restrict__ emb,
                                               float* __restrict__ h0, int N) {
  __shared__ float xs[ROWS][F];
  int r0 = blockIdx.x * ROWS;
  for (int i = threadIdx.x; i < ROWS * F; i += 128)
    xs[i >> 6][i & 63] = x[(size_t)r0 * F + i];
  __syncthreads();
  int d = threadIdx.x;
  float acc[ROWS] = {};
  for (int k = 0; k < F; ++k) {
    float ev = emb[k * H + d];
    #pragma unroll
    for (int r = 0; r < ROWS; ++r) acc[r] = fmaf(xs[r][k], ev, acc[r]);
  }
  #pragma unroll
  for (int r = 0; r < ROWS; ++r) h0[(size_t)(r0 + r) * H + d] = acc[r];
}

// ---------------- aggregation + block-diag transform ----------------
// Block = 128 threads per dst node; thread d owns channel d.
// acc[24] in VGPRs; relation select via wave-uniform scalar switch.

#define SW8(rel, base, v)                                                  \
  switch (rel) {                                                           \
    case 0: acc[(base) + 0] += (v); break;                                 \
    case 1: acc[(base) + 1] += (v); break;                                 \
    case 2: acc[(base) + 2] += (v); break;                                 \
    case 3: acc[(base) + 3] += (v); break;                                 \
    case 4: acc[(base) + 4] += (v); break;                                 \
    case 5: acc[(base) + 5] += (v); break;                                 \
    case 6: acc[(base) + 6] += (v); break;                                 \
    default: acc[(base) + 7] += (v); break;                                \
  }

#define ACCSW(uu, v)                                                       \
  do {                                                                     \
    SW8(((uu) >> 16) & 7u, 0, v);                                          \
    SW8(((uu) >> 20) & 7u, 8, v);                                          \
    SW8(((uu) >> 24) & 7u, 16, v);                                         \
  } while (0)

__global__ __launch_bounds__(128) void agg_kernel(
    const float* __restrict__ hsrc, const int* __restrict__ offs,
    const unsigned* __restrict__ elist, const int* __restrict__ cnt8,
    const float* __restrict__ Wall, float* __restrict__ m, int N) {
  const int n = blockIdx.x;
  const int d = threadIdx.x;
  __shared__ float s[D * R][H];   // 12 KB (staging for transform only)
  __shared__ float sinv[D * R];

  float acc[D * R];
  #pragma unroll
  for (int k = 0; k < D * R; ++k) acc[k] = 0.f;

  if (d < D * R) {
    int c = cnt8[n * (D * R) + d];
    sinv[d] = (c > 0) ? 1.f / (float)c : 0.f;
  }

  const int beg = offs[n], end = offs[n + 1];
  const float* __restrict__ hd = hsrc + d;

  int e = beg;
  for (; e + 4 <= end; e += 4) {
    // scalarize the (wave-uniform) packed edge words
    const unsigned u0 = __builtin_amdgcn_readfirstlane(elist[e]);
    const unsigned u1 = __builtin_amdgcn_readfirstlane(elist[e + 1]);
    const unsigned u2 = __builtin_amdgcn_readfirstlane(elist[e + 2]);
    const unsigned u3 = __builtin_amdgcn_readfirstlane(elist[e + 3]);
    // 4 independent gathers in flight
    const float v0 = hd[(size_t)(u0 & 0xFFFFu) * H];
    const float v1 = hd[(size_t)(u1 & 0xFFFFu) * H];
    const float v2 = hd[(size_t)(u2 & 0xFFFFu) * H];
    const float v3 = hd[(size_t)(u3 & 0xFFFFu) * H];
    ACCSW(u0, v0);
    ACCSW(u1, v1);
    ACCSW(u2, v2);
    ACCSW(u3, v3);
  }
  for (; e < end; ++e) {
    const unsigned u = __builtin_amdgcn_readfirstlane(elist[e]);
    const float v = hd[(size_t)(u & 0xFFFFu) * H];
    ACCSW(u, v);
  }

  #pragma unroll
  for (int k = 0; k < D * R; ++k) s[k][d] = acc[k];
  __syncthreads();

  const int b = d >> 5, dd = d & 31;
  #pragma unroll
  for (int j = 0; j < D; ++j) {
    float a = 0.f;
    for (int r = 0; r < R; ++r) {
      const int jr = j * R + r;
      const float* __restrict__ Wr = Wall + (((size_t)jr * B + b) * C) * C + dd;
      const float4* __restrict__ srow4 = (const float4*)&s[jr][b * C];
      float t = 0.f;
      #pragma unroll
      for (int c4 = 0; c4 < C / 4; ++c4) {
        const float4 sv = srow4[c4];
        t = fmaf(sv.x, Wr[(size_t)(4 * c4 + 0) * C], t);
        t = fmaf(sv.y, Wr[(size_t)(4 * c4 + 1) * C], t);
        t = fmaf(sv.z, Wr[(size_t)(4 * c4 + 2) * C], t);
        t = fmaf(sv.w, Wr[(size_t)(4 * c4 + 3) * C], t);
      }
      a = fmaf(t, sinv[jr], a);
    }
    m[((size_t)j * N + n) * H + d] = a;
  }
}

// ---------------- dense root matmul + msg add + relu ----------------

__global__ __launch_bounds__(128) void matB(
    const float* __restrict__ h, const float* __restrict__ m,
    const float* __restrict__ rootall, const float* __restrict__ biasall,
    float* __restrict__ out, int N_all, int N) {
  const int j = blockIdx.y;
  const int row0 = blockIdx.x * ROWSB;
  const int d = threadIdx.x;
  const float* root = rootall + (size_t)j * H * H;
  __shared__ float hs[ROWSB][H];

  #pragma unroll
  for (int r = 0; r < ROWSB; ++r)
    hs[r][d] = h[(size_t)(row0 + r) * H + d];
  __syncthreads();

  const float bias = biasall[j * H + d];
  float acc[ROWSB];
  #pragma unroll
  for (int r = 0; r < ROWSB; ++r) acc[r] = bias;

  for (int k = 0; k < H; ++k) {
    float rk = root[(size_t)k * H + d];
    #pragma unroll
    for (int r = 0; r < ROWSB; ++r) acc[r] = fmaf(hs[r][k], rk, acc[r]);
  }

  if (row0 + ROWSB <= N) {
    #pragma unroll
    for (int r = 0; r < ROWSB; ++r)
      acc[r] += m[((size_t)j * N + row0 + r) * H + d];
  }

  #pragma unroll
  for (int r = 0; r < ROWSB; ++r)
    out[((size_t)j * N_all + row0 + r) * H + d] = fmaxf(acc[r], 0.f);
}

// ---------------- launch ----------------

extern "C" void kernel_launch(void* const* d_in, const int* in_sizes, int n_in,
                              void* d_out, int out_size, void* d_ws, size_t ws_size,
                              hipStream_t stream) {
  const float* x    = (const float*)d_in[0];
  const int*   ei   = (const int*)d_in[1];
  const int*   attr = (const int*)d_in[2];
  const float* emb  = (const float*)d_in[3];
  const float* cw   = (const float*)d_in[4];
  const float* cr   = (const float*)d_in[5];
  const float* cb   = (const float*)d_in[6];
  float* out = (float*)d_out;

  const int N = in_sizes[0] / F;   // 20000
  const int E = in_sizes[1] / 2;   // 640000

  char* ws = (char*)d_ws;
  size_t woff = 0;
  auto alloc = [&](size_t bytes) -> void* {
    void* p = ws + woff;
    woff = (woff + bytes + 255) & ~(size_t)255;
    return p;
  };
  float*    h0     = (float*)alloc((size_t)N * H * 4);
  float*    h1     = (float*)alloc((size_t)D * N * H * 4);
  float*    m      = (float*)alloc((size_t)D * N * H * 4);
  int*      indeg  = (int*)alloc((size_t)N * 4);
  int*      cnt8   = (int*)alloc((size_t)N * D * R * 4);
  int*      cexcl  = (int*)alloc((size_t)N * 4);
  int*      bsum   = (int*)alloc(4096);
  int*      offs   = (int*)alloc((size_t)(N + 1) * 4);
  int*      cursor = (int*)alloc((size_t)N * 4);
  unsigned* elist  = (unsigned*)alloc((size_t)E * 4);

  hipMemsetAsync(cnt8, 0, (size_t)N * D * R * 4, stream);
  count_edges<<<(E + 255) / 256, 256, 0, stream>>>(ei, attr, cnt8, E);
  indeg_from_cnt8<<<(N + 255) / 256, 256, 0, stream>>>(cnt8, indeg, N);

  int nch = (N + SCAN_CHUNK - 1) / SCAN_CHUNK;  // 40
  scan_a<<<nch, SCAN_CHUNK, 0, stream>>>(indeg, cexcl, bsum, N);
  scan_b<<<1, 1024, 0, stream>>>(bsum, nch);
  scan_c<<<(N + 255) / 256, 256, 0, stream>>>(cexcl, bsum, offs, N, E);
  copy_int<<<(N + 255) / 256, 256, 0, stream>>>(offs, cursor, N);
  fill_edges<<<(E + 255) / 256, 256, 0, stream>>>(ei, attr, cursor, elist, E);

  gemm_h0<<<N / ROWS, 128, 0, stream>>>(x, emb, h0, N);

  // layer 0
  agg_kernel<<<N, 128, 0, stream>>>(h0, offs, elist, cnt8, cw, m, N);
  {
    dim3 grid(N / ROWSB, D);
    matB<<<grid, 128, 0, stream>>>(h0, m, cr, cb, h1, N, N);
  }
  // layer 1 (gathers only rows < N of h1)
  agg_kernel<<<N, 128, 0, stream>>>(h1, offs, elist, cnt8,
                                    cw + (size_t)D * R * B * C * C, m, N);
  {
    dim3 grid((D * N) / ROWSB, D);
    matB<<<grid, 128, 0, stream>>>(h1, m,
                                   cr + (size_t)D * H * H,
                                   cb + (size_t)D * H,
                                   out, D * N, N);
  }
}